// Round 10
// baseline (284.206 us; speedup 1.0000x reference)
//
#include <hip/hip_runtime.h>
#include <hip/hip_bf16.h>

#define N_NODES 50000
#define N_EDGES 600000
#define N_GRAPHS 100
#define M_PAD 50176  // 392 * 128
#define TSLICE ((size_t)M_PAD * 32)   // elements per 32-col tile slice

typedef __bf16 bf16_t;
typedef __attribute__((ext_vector_type(8))) __bf16 bf16x8;
typedef __attribute__((ext_vector_type(4))) __bf16 bf16x4;
typedef __attribute__((ext_vector_type(4))) float f32x4;

// ---------------- degree + per-edge rank (atomicAdd return value) ----------------
__global__ void degk(const int* __restrict__ dst, int* __restrict__ deg,
                     int* __restrict__ rank, int n) {
    int i = blockIdx.x * 256 + threadIdx.x;
    if (i < n) rank[i] = atomicAdd(&deg[dst[i]], 1);
}

// ---------------- scan part 1: per-1024-chunk inclusive scan + norm ----------------
__global__ __launch_bounds__(1024) void scan1(const int* __restrict__ deg,
                                              int* __restrict__ row_off,
                                              int* __restrict__ partial,
                                              float* __restrict__ norm, int n) {
    __shared__ int buf[1024];
    int i = blockIdx.x * 1024 + threadIdx.x;
    int v = (i < n) ? deg[i] : 0;
    buf[threadIdx.x] = v;
    __syncthreads();
    for (int off = 1; off < 1024; off <<= 1) {
        int t = (threadIdx.x >= off) ? buf[threadIdx.x - off] : 0;
        __syncthreads();
        buf[threadIdx.x] += t;
        __syncthreads();
    }
    if (i < n) {
        row_off[i + 1] = buf[threadIdx.x];
        float d = fmaxf((float)v, 1.0f);
        norm[i] = 1.0f / sqrtf(d);
    }
    if (threadIdx.x == 1023) partial[blockIdx.x] = buf[1023];  // chunk total
}

// ---------------- scan part 2 (fused): add prefix of chunk totals ----------------
__global__ __launch_bounds__(256) void scan3(int* __restrict__ row_off,
                                             const int* __restrict__ partial, int n) {
    int i = blockIdx.x * 256 + threadIdx.x;
    int c = (blockIdx.x * 256) >> 10;    // chunk index of this block
    __shared__ int pre;
    if (threadIdx.x < 64) {
        int v = (threadIdx.x < c) ? partial[threadIdx.x] : 0;
        for (int off = 32; off; off >>= 1) v += __shfl_down(v, off, 64);
        if (threadIdx.x == 0) pre = v;
    }
    __syncthreads();
    if (i == 0) row_off[0] = 0;
    if (i < n) row_off[i + 1] += pre;
}

// ---------------- fused mid kernel: prescale(tile-major) | CSR scatter | W permute ---
#define NPRE 6250                       // N_NODES*32/256
#define NSC  ((N_EDGES + 255) / 256)    // 2344
#define NPW  ((384 * 192 + 255) / 256)  // 288
__global__ __launch_bounds__(256) void midk(const float* __restrict__ x,
                                            const float* __restrict__ norm,
                                            bf16_t* __restrict__ xb, bf16_t* __restrict__ xs,
                                            const int* __restrict__ src, const int* __restrict__ dst,
                                            const int* __restrict__ row_off,
                                            const int* __restrict__ rank,
                                            int* __restrict__ csr_src,
                                            const float* __restrict__ W1, bf16_t* __restrict__ Wp1,
                                            const float* __restrict__ W2, bf16_t* __restrict__ Wp2) {
    int b = blockIdx.x;
    if (b < NPRE) {
        // prescale: one thread per float4; tile-major xb = bf16(x), xs = bf16(x*norm)
        int i = b * 256 + threadIdx.x;
        int node = i >> 5, c4 = i & 31;
        float4 v = *(const float4*)(x + (size_t)node * 128 + c4 * 4);
        float nd = norm[node];
        bf16x4 ob, os;
        ob[0] = (bf16_t)v.x; ob[1] = (bf16_t)v.y; ob[2] = (bf16_t)v.z; ob[3] = (bf16_t)v.w;
        os[0] = (bf16_t)(v.x * nd); os[1] = (bf16_t)(v.y * nd);
        os[2] = (bf16_t)(v.z * nd); os[3] = (bf16_t)(v.w * nd);
        size_t t = (size_t)(c4 >> 3) * TSLICE + (size_t)node * 32 + (c4 & 7) * 4;
        *(bf16x4*)(xb + t) = ob;
        *(bf16x4*)(xs + t) = os;
    } else if (b < NPRE + NSC) {
        // CSR scatter: atomic-free (rank precomputed in degk)
        int e = (b - NPRE) * 256 + threadIdx.x;
        if (e >= N_EDGES) return;
        int d = dst[e];
        csr_src[row_off[d] + rank[e]] = src[e];
    } else {
        int i = (b - NPRE - NSC) * 256 + threadIdx.x;
        if (i < 384 * 128) {
            // W1: K=384, N=128 -> NT=8 fragment layout (unchanged)
            int k = i >> 7, n = i & 127;
            int kt = k >> 5, q = (k >> 3) & 3, j = k & 7;
            int nt = n >> 4, ln = n & 15;
            Wp1[(((size_t)kt * 8 + nt) * 64 + q * 16 + ln) * 8 + j] = (bf16_t)W1[i];
        } else if (i < 384 * 128 + 384 * 64) {
            // W2 commuted: B[kk, blk*64+n] = W2[blk*128+kk, n]; K=128, N=192 -> NT=12
            int idx = i - 384 * 128;
            int k384 = idx >> 6, n = idx & 63;
            int blk = k384 >> 7, kk = k384 & 127;
            int col = blk * 64 + n;
            int kt = kk >> 5, q = (kk >> 3) & 3, j = kk & 7;
            int nt = col >> 4, ln = col & 15;
            Wp2[(((size_t)kt * 12 + nt) * 64 + q * 16 + ln) * 8 + j] = (bf16_t)W2[idx];
        }
    }
}

// ---------------- XCD-spatial SpMM, edge-parallel halves, single-exposure gathers ----
// 8 threads/node: half = edge-parity (2-way edge parallel), l = col chunk (4 x 8 cols).
// Typical node (deg<=16): ONE batch of 8 clamped+masked gathers per half -> one
// latency exposure. Cross-half merge via shfl_xor(4). half0 stores out_c, half1 out_s.
template <int TILES, bool SCALED>
__global__ __launch_bounds__(256) void spmm8(const bf16_t* __restrict__ in,
                                             bf16_t* __restrict__ out_c,
                                             bf16_t* __restrict__ out_s,
                                             const float* __restrict__ norm,
                                             const int* __restrict__ row_off,
                                             const int* __restrict__ csr, int n) {
    constexpr int PARTS = 8 / TILES;          // XCDs sharing one tile
    int bid  = blockIdx.x;
    int xcd  = bid & 7;
    int tile = xcd / PARTS;
    int part = xcd % PARTS;
    int sub  = bid >> 3;
    int grp  = threadIdx.x >> 3;              // 32 nodes per block
    int half = (threadIdx.x >> 2) & 1;
    int l    = threadIdx.x & 3;               // cols [l*8, l*8+8)
    int node = (sub * PARTS + part) * 32 + grp;
    if (node >= n) return;
    int e0 = row_off[node], e1 = row_off[node + 1];
    const bf16_t* base = in + (size_t)tile * TSLICE + l * 8;
    float acc[8] = {};
    if (e0 < e1) {
        int be   = e0 + half;
        int cnt  = (e1 - be + 1) >> 1;        // edges this half handles (stride 2)
        int emax = e1 - 1;
        int s[8];
#pragma unroll
        for (int k = 0; k < 8; k++) s[k] = csr[min(be + 2 * k, emax)];
        bf16x8 v[8];
#pragma unroll
        for (int k = 0; k < 8; k++) v[k] = *(const bf16x8*)(base + (size_t)s[k] * 32);
#pragma unroll
        for (int k = 0; k < 8; k++) {
            float wk = (k < cnt) ? 1.0f : 0.0f;
#pragma unroll
            for (int j = 0; j < 8; j++) acc[j] += wk * (float)v[k][j];
        }
        // rare overflow: deg > 16
        for (int e = be + 16; e < e1; e += 2) {
            int ss = csr[e];
            bf16x8 vv = *(const bf16x8*)(base + (size_t)ss * 32);
#pragma unroll
            for (int j = 0; j < 8; j++) acc[j] += (float)vv[j];
        }
    }
#pragma unroll
    for (int j = 0; j < 8; j++) acc[j] += __shfl_xor(acc[j], 4, 64);
    float nd = norm[node];
    size_t t = (size_t)tile * TSLICE + (size_t)node * 32 + l * 8;
    if (half == 0) {
        bf16x8 oc;
#pragma unroll
        for (int j = 0; j < 8; j++) oc[j] = (bf16_t)(acc[j] * nd);
        __builtin_nontemporal_store(oc, (bf16x8*)(out_c + t));
    } else if (SCALED) {
        float n2 = nd * nd;
        bf16x8 os;
#pragma unroll
        for (int j = 0; j < 8; j++) os[j] = (bf16_t)(acc[j] * n2);
        __builtin_nontemporal_store(os, (bf16x8*)(out_s + t));
    }
}

// ---------------- layer-1 MFMA concat-GEMM: hL1 = relu([xb|c1|c2] @ W1 + b1) --------
__global__ __launch_bounds__(256) void gemm1k(const bf16_t* __restrict__ f0,
                                              const bf16_t* __restrict__ f1,
                                              const bf16_t* __restrict__ f2,
                                              const bf16_t* __restrict__ Wp,
                                              const float* __restrict__ bias,
                                              bf16_t* __restrict__ outb, int M) {
    int wave = threadIdx.x >> 6;
    int lane = threadIdx.x & 63;
    int q = lane >> 4, ln = lane & 15;
    int row0 = blockIdx.x * 128 + wave * 32;

    f32x4 acc[2][8] = {};
    const bf16_t* feats[3] = {f0, f1, f2};
    const bf16x8* Wf = (const bf16x8*)Wp;

#pragma unroll
    for (int kc = 0; kc < 12; kc++) {
        const bf16_t* A = feats[kc >> 2] + (size_t)(kc & 3) * TSLICE + q * 8;
        bf16x8 a0 = *(const bf16x8*)(A + (size_t)(row0 + ln) * 32);
        bf16x8 a1 = *(const bf16x8*)(A + (size_t)(row0 + 16 + ln) * 32);
        const bf16x8* Bp = Wf + (size_t)kc * 8 * 64 + lane;
#pragma unroll
        for (int nt = 0; nt < 8; nt++) {
            bf16x8 b = Bp[nt * 64];
            acc[0][nt] = __builtin_amdgcn_mfma_f32_16x16x32_bf16(a0, b, acc[0][nt], 0, 0, 0);
            acc[1][nt] = __builtin_amdgcn_mfma_f32_16x16x32_bf16(a1, b, acc[1][nt], 0, 0, 0);
        }
    }

    float bv[8];
#pragma unroll
    for (int nt = 0; nt < 8; nt++) bv[nt] = bias[nt * 16 + ln];

#pragma unroll
    for (int mt = 0; mt < 2; mt++) {
#pragma unroll
        for (int r = 0; r < 4; r++) {
            int row = row0 + mt * 16 + q * 4 + r;
            if (row >= M) continue;
#pragma unroll
            for (int nt = 0; nt < 8; nt++) {
                float val = fmaxf(acc[mt][nt][r] + bv[nt], 0.f);
                outb[(size_t)(nt >> 1) * TSLICE + (size_t)row * 32 + (nt & 1) * 16 + ln] = (bf16_t)val;
            }
        }
    }
}

// ---------------- layer-2 pre-GEMM (W-commute): t0 = hW20+b2 ; uvs = norm*[hW21|hW22]
__global__ __launch_bounds__(256) void gemm2k(const bf16_t* __restrict__ h,
                                              const bf16_t* __restrict__ Wp,
                                              const float* __restrict__ bias,
                                              const float* __restrict__ norm,
                                              float* __restrict__ t0,
                                              bf16_t* __restrict__ uvs, int M) {
    int wave = threadIdx.x >> 6;
    int lane = threadIdx.x & 63;
    int q = lane >> 4, ln = lane & 15;
    int row0 = blockIdx.x * 128 + wave * 32;

    f32x4 acc[2][12] = {};
    const bf16x8* Wf = (const bf16x8*)Wp;

#pragma unroll
    for (int kc = 0; kc < 4; kc++) {
        const bf16_t* A = h + (size_t)kc * TSLICE + q * 8;
        bf16x8 a0 = *(const bf16x8*)(A + (size_t)(row0 + ln) * 32);
        bf16x8 a1 = *(const bf16x8*)(A + (size_t)(row0 + 16 + ln) * 32);
        const bf16x8* Bp = Wf + (size_t)kc * 12 * 64 + lane;
#pragma unroll
        for (int nt = 0; nt < 12; nt++) {
            bf16x8 b = Bp[nt * 64];
            acc[0][nt] = __builtin_amdgcn_mfma_f32_16x16x32_bf16(a0, b, acc[0][nt], 0, 0, 0);
            acc[1][nt] = __builtin_amdgcn_mfma_f32_16x16x32_bf16(a1, b, acc[1][nt], 0, 0, 0);
        }
    }

    float bv[4];
#pragma unroll
    for (int nt = 0; nt < 4; nt++) bv[nt] = bias[nt * 16 + ln];

#pragma unroll
    for (int mt = 0; mt < 2; mt++) {
#pragma unroll
        for (int r = 0; r < 4; r++) {
            int row = row0 + mt * 16 + q * 4 + r;
            if (row >= M) continue;
            float nd = norm[row];
#pragma unroll
            for (int nt = 0; nt < 4; nt++)   // t0 = hW20 + b2 (fp32, NO relu)
                __builtin_nontemporal_store(acc[mt][nt][r] + bv[nt],
                                            t0 + (size_t)row * 64 + nt * 16 + ln);
#pragma unroll
            for (int nt = 4; nt < 12; nt++) { // uvs = norm*[hW21|hW22], tile-major
                int col = (nt - 4) * 16 + ln;
                uvs[(size_t)(col >> 5) * TSLICE + (size_t)row * 32 + (col & 31)] =
                    (bf16_t)(acc[mt][nt][r] * nd);
            }
        }
    }
}

// ---------------- fused final: relu(t0 + Au + A2v) -> per-graph max pool ------------
__global__ __launch_bounds__(256) void finpool(const float* __restrict__ t0,
                                               const bf16_t* __restrict__ Au,
                                               const bf16_t* __restrict__ A2v,
                                               const int* __restrict__ gid,
                                               unsigned int* __restrict__ out, int n) {
    int wave = threadIdx.x >> 6;
    int lane = threadIdx.x & 63;
    int n0 = blockIdx.x * 256 + wave * 64;
    if (n0 >= n) return;
    int n1 = min(n0 + 64, n);
    size_t cb = (size_t)(lane >> 5) * TSLICE + (lane & 31);
    int cur = gid[n0];
    float m = 0.f;
    for (int i = n0; i < n1; i++) {
        int g = gid[i];
        float v = fmaxf(t0[(size_t)i * 64 + lane]
                        + (float)Au[cb + (size_t)i * 32]
                        + (float)A2v[cb + (size_t)i * 32], 0.f);
        if (g != cur) { atomicMax(&out[cur * 64 + lane], __float_as_uint(m)); cur = g; m = v; }
        else m = fmaxf(m, v);
    }
    atomicMax(&out[cur * 64 + lane], __float_as_uint(m));
}

extern "C" void kernel_launch(void* const* d_in, const int* in_sizes, int n_in,
                              void* d_out, int out_size, void* d_ws, size_t ws_size,
                              hipStream_t stream) {
    const float* x  = (const float*)d_in[0];
    const float* W1 = (const float*)d_in[1];
    const float* b1 = (const float*)d_in[2];
    const float* W2 = (const float*)d_in[3];
    const float* b2 = (const float*)d_in[4];
    const int* src  = (const int*)d_in[5];
    const int* dst  = (const int*)d_in[6];
    const int* gid  = (const int*)d_in[7];
    float* out = (float*)d_out;

    char* ws = (char*)d_ws;
    size_t off = 0;
    auto take = [&](size_t bytes) {
        void* p = ws + off;
        off = (off + bytes + 255) & ~(size_t)255;
        return p;
    };
    int* deg     = (int*)take((size_t)N_NODES * 4);
    size_t zero_bytes = off;
    float* norm  = (float*)take((size_t)N_NODES * 4);
    int* row_off = (int*)take((size_t)(N_NODES + 1) * 4);
    int* partial = (int*)take(64 * 4);
    int* rank    = (int*)take((size_t)N_EDGES * 4);
    int* csr_src = (int*)take((size_t)N_EDGES * 4);
    bf16_t* Wp1  = (bf16_t*)take((size_t)384 * 128 * 2);
    bf16_t* Wp2  = (bf16_t*)take((size_t)384 * 64 * 2);
    bf16_t* B0 = (bf16_t*)take((size_t)M_PAD * 128 * 2);  // xb  (4-tile)
    bf16_t* B1 = (bf16_t*)take((size_t)M_PAD * 128 * 2);  // xs  (4-tile)
    bf16_t* B2 = (bf16_t*)take((size_t)M_PAD * 128 * 2);  // c1  = A~x
    bf16_t* B3 = (bf16_t*)take((size_t)M_PAD * 128 * 2);  // c1s = norm*A~x
    bf16_t* B4 = (bf16_t*)take((size_t)M_PAD * 128 * 2);  // c2  = A~^2 x
    bf16_t* B5 = (bf16_t*)take((size_t)M_PAD * 128 * 2);  // hL1 (4-tile)
    float*  B6 = (float*)take((size_t)M_PAD * 64 * 4);    // t0 = hW20+b2 (fp32)
    bf16_t* B7 = (bf16_t*)take((size_t)M_PAD * 128 * 2);  // uvs = norm*[u|v]
    bf16_t* B8 = (bf16_t*)take((size_t)M_PAD * 128 * 2);  // [A~u | A~v]
    bf16_t* B9 = (bf16_t*)take((size_t)M_PAD * 128 * 2);  // norm*[A~u|A~v]
    bf16_t* B10= (bf16_t*)take((size_t)M_PAD * 128 * 2);  // A~^2 v (2-tile, 64c)
    (void)ws_size; (void)in_sizes; (void)n_in; (void)out_size;

    hipMemsetAsync(d_ws, 0, zero_bytes, stream);
    hipMemsetAsync(d_out, 0, (size_t)N_GRAPHS * 64 * 4, stream);

    degk<<<(N_EDGES + 255) / 256, 256, 0, stream>>>(dst, deg, rank, N_EDGES);
    int nchunks = (N_NODES + 1023) / 1024;
    scan1<<<nchunks, 1024, 0, stream>>>(deg, row_off, partial, norm, N_NODES);
    scan3<<<(N_NODES + 255) / 256, 256, 0, stream>>>(row_off, partial, N_NODES);
    midk<<<NPRE + NSC + NPW, 256, 0, stream>>>(x, norm, B0, B1, src, dst, row_off, rank,
                                               csr_src, W1, Wp1, W2, Wp2);

    int grid4 = 8 * ((N_NODES + 63) / 64);   // TILES=4: 2 XCDs/tile, 32 nodes/block
    int grid2 = 8 * ((N_NODES + 127) / 128); // TILES=2: 4 XCDs/tile
    int gemm_grid = M_PAD / 128;             // 392

    // layer 1 hops
    spmm8<4, true ><<<grid4, 256, 0, stream>>>(B1, B2, B3, norm, row_off, csr_src, N_NODES);
    spmm8<4, false><<<grid4, 256, 0, stream>>>(B3, B4, nullptr, norm, row_off, csr_src, N_NODES);
    // layer 1 GEMM -> hL1
    gemm1k<<<gemm_grid, 256, 0, stream>>>(B0, B2, B4, Wp1, b1, B5, N_NODES);
    // layer 2 pre-GEMM (W-commute): t0, uvs
    gemm2k<<<gemm_grid, 256, 0, stream>>>(B5, Wp2, b2, norm, B6, B7, N_NODES);
    // layer 2 hops: A on [u|v] (128c), B on norm*A~v (64c = tiles 2,3 of B9)
    spmm8<4, true ><<<grid4, 256, 0, stream>>>(B7, B8, B9, norm, row_off, csr_src, N_NODES);
    spmm8<2, false><<<grid2, 256, 0, stream>>>(B9 + 2 * TSLICE, B10, nullptr, norm, row_off, csr_src, N_NODES);
    // fused add + relu + readout
    finpool<<<(N_NODES + 255) / 256, 256, 0, stream>>>(B6, B8, B10, gid, (unsigned int*)out, N_NODES);
}